// Round 6
// baseline (231.773 us; speedup 1.0000x reference)
//
#include <hip/hip_runtime.h>
#include <cstdint>

#define NPTS   16384
#define BATCH  4
#define BNP    65536
#define CIN    64
#define KNB    16
#define COUT   128
#define BN_EPS 1e-5f

typedef __attribute__((ext_vector_type(8))) short     short8;
typedef __attribute__((ext_vector_type(4))) float     f32x4;
typedef __attribute__((ext_vector_type(2))) unsigned  u32x2;
typedef __attribute__((ext_vector_type(4))) int       i32x4;

__device__ __forceinline__ unsigned short f2bf(float f) {   // RNE
    unsigned u = __float_as_uint(f);
    u += 0x7FFFu + ((u >> 16) & 1u);
    return (unsigned short)(u >> 16);
}
__device__ __forceinline__ float bf2f(unsigned short h) {
    return __uint_as_float(((unsigned)h) << 16);
}

// ---- K0: feature [B][C][N] -> flat bf16 [B*N][64]; blk 1024: stat + weight cvt ----
__global__ __launch_bounds__(256) void k_prep(const float* __restrict__ feat,
                                              unsigned short* __restrict__ fb,
                                              float* __restrict__ stat,
                                              const float* __restrict__ Wm,
                                              const float* __restrict__ Wc,
                                              unsigned short* __restrict__ wmb,
                                              unsigned short* __restrict__ wcb)
{
    if (blockIdx.x == 1024) {           // aux block: zero BN accum, bf16-ify weights
        stat[threadIdx.x] = 0.f;        // 256 floats: [0..127]=sum, [128..255]=sumsq
        #pragma unroll
        for (int i = threadIdx.x; i < CIN * CIN; i += 256)       wmb[i] = f2bf(Wm[i]);
        #pragma unroll
        for (int i = threadIdx.x; i < COUT * CIN; i += 256)      wcb[i] = f2bf(Wc[i]);
        return;
    }
    __shared__ float t[CIN][CIN + 1];
    int blk = blockIdx.x;
    int b   = blk >> 8;
    int n0  = (blk & 255) << 6;
    int sub = threadIdx.x >> 6, lane = threadIdx.x & 63;
    const float* fp = feat + (size_t)b * CIN * NPTS;
    #pragma unroll
    for (int r = 0; r < CIN; r += 4) {
        int c = r + sub;
        t[c][lane] = fp[(size_t)c * NPTS + n0 + lane];     // coalesced along n
    }
    __syncthreads();
    unsigned short* ob = fb + (size_t)(b * NPTS + n0) * CIN;
    #pragma unroll
    for (int r = 0; r < CIN; r += 4) {
        int x = r + sub;
        ob[(size_t)x * CIN + lane] = f2bf(t[lane][x]);     // row n0+x, ch=lane
    }
}

// ---------------- K1: gather+attention+linear, REGISTER-staged gather ------------------
// Round-5 diagnosis: global_load_lds + ds_read of the same LDS forces a compiler
// vmcnt(0) drain every k-iter (~4700 cy/iter measured vs ~400 compute). Fix: the
// 16B/lane the gather fetches in the (ptc,qg) mapping IS the phase-1 B-fragment,
// so gather straight into VGPRs (3-deep ring, compiler emits counted vmcnt on the
// exact registers). P-inputs re-read as 8B loads from the same (L1-hot) lines.
// LDS in the k-loop: only the 9.2KB plds transpose (plain ds ops, precise lgkmcnt).
// acc2 stays MFMA-accumulated (AGPRs) -- do NOT go pool-first (round-2/4 spill trap).
__global__ __launch_bounds__(256, 2) void k_main(
    const unsigned short* __restrict__ fb,   // [BNP][64] bf16
    const int* __restrict__ nidx,            // [BNP][16]
    const unsigned short* __restrict__ wmb,  // [64][64] bf16
    const unsigned short* __restrict__ wcb,  // [128][64] bf16
    float* __restrict__ out,                 // [4][128][16384], pre-BN
    float* __restrict__ stat)                // [256]: ch sums / sumsq
{
    // arena: k-loop uses [0,9216) as plds [4 wv][1152 u16];
    // epilogue overlays f32 st[128][64] on [0,32768)
    __shared__ __align__(16) char arena[32768];
    unsigned short* plds = (unsigned short*)arena;

    const int tid  = threadIdx.x;
    const int wv   = tid >> 6;
    const int lane = tid & 63;
    const int ptc  = lane & 15;     // MFMA n / m index; also gather row owner
    const int qg   = lane >> 4;     // quad group: owns ch qg*8..+7 (+32)
    const int p4   = ptc * 4;

    const int g = blockIdx.x * 4 + wv;       // this wave's group (16 points)

    // ---- weight A-fragments in registers: A[m=lane&15][k=qg*8+j (+32*ks)] ----
    short8 wmF[4][2];
    #pragma unroll
    for (int mt = 0; mt < 4; ++mt)
        #pragma unroll
        for (int ks = 0; ks < 2; ++ks)
            wmF[mt][ks] = *(const short8*)&wmb[(size_t)(mt * 16 + ptc) * CIN + qg * 8 + ks * 32];
    short8 wcF[8][2];
    #pragma unroll
    for (int mt = 0; mt < 8; ++mt)
        #pragma unroll
        for (int ks = 0; ks < 2; ++ks)
            wcF[mt][ks] = *(const short8*)&wcb[(size_t)(mt * 16 + ptc) * CIN + qg * 8 + ks * 32];

    f32x4 acc2[8];
    #pragma unroll
    for (int i = 0; i < 8; ++i) acc2[i] = (f32x4){0.f, 0.f, 0.f, 0.f};

    // ---- group's 256 neighbor indices: lane holds idx[lane>>2][4*(lane&3)..+3] ----
    i32x4 iv = *(const i32x4*)(nidx + (size_t)g * 256 + lane * 4);

    // ---- register gather ring, depth 3 (fully unrolled loop -> static indices) ----
    // lane (ptc,qg) loads row id=idx[ptc][k]: b1_0 = ch qg*8..+7, b1_1 = ch 32+qg*8..+7
    short8 rb0[3], rb1[3];
    int    rid[3];
    #pragma unroll
    for (int kk = 0; kk < 3; ++kk) {
        int id = __shfl(iv[kk & 3], p4 + (kk >> 2));       // idx[ptc][kk]
        rid[kk] = id;
        const unsigned short* gp = fb + (size_t)id * CIN;
        rb0[kk] = *(const short8*)(gp + qg * 8);
        rb1[kk] = *(const short8*)(gp + 32 + qg * 8);
    }

    #pragma unroll
    for (int k = 0; k < KNB; ++k) {
        const int sl = k % 3;                              // static under full unroll

        // ---- P-input re-loads for this k (same 2 cache lines as rb: L1/L2 hot) ----
        // sv[mt] = fb_row[ch 16mt+4qg .. +3], issued early, consumed after softmax
        const unsigned short* rp = fb + (size_t)rid[sl] * CIN;
        u32x2 sv0 = *(const u32x2*)(rp +  0 + qg * 4);
        u32x2 sv1 = *(const u32x2*)(rp + 16 + qg * 4);
        u32x2 sv2 = *(const u32x2*)(rp + 32 + qg * 4);
        u32x2 sv3 = *(const u32x2*)(rp + 48 + qg * 4);

        // ---- phase 1: score^T[d, pt] = Wm x spir^T (B-frags direct from ring) ----
        short8 b1_0 = rb0[sl];
        short8 b1_1 = rb1[sl];
        f32x4 zero4 = (f32x4){0.f, 0.f, 0.f, 0.f};
        f32x4 a1[4];
        #pragma unroll
        for (int mt = 0; mt < 4; ++mt) {
            f32x4 t0 = __builtin_amdgcn_mfma_f32_16x16x32_bf16(wmF[mt][0], b1_0, zero4, 0, 0, 0);
            a1[mt]   = __builtin_amdgcn_mfma_f32_16x16x32_bf16(wmF[mt][1], b1_1, t0,    0, 0, 0);
        }

        // ---- refill ring: issue gather k+3 (consumed 3 iters later) ----
        if (k + 3 < KNB) {
            int id = __shfl(iv[(k + 3) & 3], p4 + ((k + 3) >> 2));
            rid[sl] = id;
            const unsigned short* gp = fb + (size_t)id * CIN;
            rb0[sl] = *(const short8*)(gp + qg * 8);
            rb1[sl] = *(const short8*)(gp + 32 + qg * 8);
        }

        // ---- softmax over d: exp in place + xor16/xor32 ----
        float s = 0.f;
        #pragma unroll
        for (int mt = 0; mt < 4; ++mt)
            #pragma unroll
            for (int r = 0; r < 4; ++r) {
                float x = __expf(a1[mt][r]);
                a1[mt][r] = x;
                s += x;
            }
        s += __shfl_xor(s, 16);
        s += __shfl_xor(s, 32);
        float inv = __builtin_amdgcn_rcpf(s);

        // ---- P = attn (.) spir  -> plds (bf16, B-layout staging) ----
        unsigned short* pl = plds + wv * 1152;
        #pragma unroll
        for (int mt = 0; mt < 4; ++mt) {
            u32x2 sv = (mt == 0) ? sv0 : (mt == 1) ? sv1 : (mt == 2) ? sv2 : sv3;
            unsigned lo = sv[0], hi = sv[1];
            float p0 = bf2f((unsigned short)lo)         * (a1[mt][0] * inv);
            float p1 = bf2f((unsigned short)(lo >> 16)) * (a1[mt][1] * inv);
            float p2 = bf2f((unsigned short)hi)         * (a1[mt][2] * inv);
            float p3 = bf2f((unsigned short)(hi >> 16)) * (a1[mt][3] * inv);
            unsigned w0 = ((__float_as_uint(p0) + 0x8000u) >> 16) |
                          ((__float_as_uint(p1) + 0x8000u) & 0xFFFF0000u);
            unsigned w1 = ((__float_as_uint(p2) + 0x8000u) >> 16) |
                          ((__float_as_uint(p3) + 0x8000u) & 0xFFFF0000u);
            *(u32x2*)&pl[ptc * 72 + mt * 16 + qg * 4] = (u32x2){w0, w1};
        }

        // ---- B2 frags: P[pt=lane&15][d=qg*8+j+32ks] ----
        short8 b2_0 = *(const short8*)&pl[ptc * 72 +      qg * 8];
        short8 b2_1 = *(const short8*)&pl[ptc * 72 + 32 + qg * 8];

        // ---- phase 2: acc2[o, pt] += Wc x P_k (fused pool+linear; acc2 -> AGPRs) ----
        #pragma unroll
        for (int mt = 0; mt < 8; ++mt) {
            acc2[mt] = __builtin_amdgcn_mfma_f32_16x16x32_bf16(wcF[mt][0], b2_0, acc2[mt], 0, 0, 0);
            acc2[mt] = __builtin_amdgcn_mfma_f32_16x16x32_bf16(wcF[mt][1], b2_1, acc2[mt], 0, 0, 0);
        }
    }

    // ---- stage block's 64x128 output tile into LDS (arena reused; all waves done) ----
    __syncthreads();
    float* st = (float*)arena;                     // [128 ch][64 pts], 32 KB exact
    #pragma unroll
    for (int mt = 0; mt < 8; ++mt)
        #pragma unroll
        for (int r = 0; r < 4; ++r) {
            int ch = mt * 16 + qg * 4 + r;
            int f  = (wv * 16 + ptc) ^ ((ch & 7) << 2);    // bank swizzle, low-way
            st[ch * 64 + f] = acc2[mt][r];
        }
    __syncthreads();

    // ---- cooperative full-line stores (256B contiguous per channel) + BN partials ----
    const int b  = blockIdx.x >> 8;                // 64 points per block, 16384 per batch
    const int n0 = (blockIdx.x * 64) & (NPTS - 1);
    float s_acc[8], q_acc[8];
    #pragma unroll
    for (int i = 0; i < 8; ++i) {
        int flat = i * 256 + tid;
        int ch   = flat >> 4;                      // = i*16 + (tid>>4)
        int slot = flat & 15;
        int f0   = (slot * 4) ^ ((ch & 7) << 2);   // un-swizzle: yields pts slot*4..+3
        f32x4 v  = *(const f32x4*)&st[ch * 64 + f0];
        *(f32x4*)(out + (((size_t)(b * COUT + ch)) << 14) + n0 + slot * 4) = v;
        s_acc[i] = (v[0] + v[1]) + (v[2] + v[3]);
        q_acc[i] = (v[0]*v[0] + v[1]*v[1]) + (v[2]*v[2] + v[3]*v[3]);
    }
    // reduce over the 16 threads sharing each channel (aligned 16-lane groups in-wave)
    #pragma unroll
    for (int m = 1; m <= 8; m <<= 1)
        #pragma unroll
        for (int i = 0; i < 8; ++i) {
            s_acc[i] += __shfl_xor(s_acc[i], m);
            q_acc[i] += __shfl_xor(q_acc[i], m);
        }
    if ((tid & 15) == 0) {
        #pragma unroll
        for (int i = 0; i < 8; ++i) {
            int ch = i * 16 + (tid >> 4);
            atomicAdd(&stat[ch],        s_acc[i]);
            atomicAdd(&stat[COUT + ch], q_acc[i]);
        }
    }
}

// ---------------- K2: finalize stats per block + apply BN in place ----------------
__global__ __launch_bounds__(256) void k_apply(float* __restrict__ out,
                                               const float* __restrict__ stat,
                                               const float* __restrict__ gamma,
                                               const float* __restrict__ beta)
{
    __shared__ float sc[COUT], sh[COUT];
    int t = threadIdx.x;
    if (t < COUT) {
        float S = stat[t], Q = stat[COUT + t];
        float mean = S * (1.0f / BNP);
        float var  = Q * (1.0f / BNP) - mean * mean;
        float a = gamma[t] * rsqrtf(var + BN_EPS);
        sc[t] = a; sh[t] = beta[t] - mean * a;
    }
    __syncthreads();
    const int total4 = BATCH * COUT * NPTS / 4;
    for (long i = (long)blockIdx.x * 256 + t; i < total4; i += (long)gridDim.x * 256) {
        int ch = ((int)(i >> 12)) & 127;
        float4 v = ((float4*)out)[i];
        float a = sc[ch], b2 = sh[ch];
        v.x = fmaf(v.x, a, b2); v.y = fmaf(v.y, a, b2);
        v.z = fmaf(v.z, a, b2); v.w = fmaf(v.w, a, b2);
        ((float4*)out)[i] = v;
    }
}

extern "C" void kernel_launch(void* const* d_in, const int* in_sizes, int n_in,
                              void* d_out, int out_size, void* d_ws, size_t ws_size,
                              hipStream_t stream)
{
    const float* feat  = (const float*)d_in[0];
    const int*   nidx  = (const int*)  d_in[1];
    // d_in[2] = permatrix (unused); d_in[5] = b_conv (exactly absorbed by BN)
    const float* Wm    = (const float*)d_in[3];
    const float* Wc    = (const float*)d_in[4];
    const float* gamma = (const float*)d_in[6];
    const float* beta  = (const float*)d_in[7];
    float* out = (float*)d_out;

    char* ws = (char*)d_ws;
    unsigned short* fb   = (unsigned short*)ws;                       // 8.39 MB
    float*          stat = (float*)(ws + (size_t)BNP * CIN * 2);      // 1 KB
    unsigned short* wmb  = (unsigned short*)(ws + (size_t)BNP * CIN * 2 + 1024);
    unsigned short* wcb  = wmb + CIN * CIN;                           // 8 KB + 16 KB

    k_prep <<<1025, 256, 0, stream>>>(feat, fb, stat, Wm, Wc, wmb, wcb);
    k_main <<<1024, 256, 0, stream>>>(fb, nidx, wmb, wcb, out, stat);
    k_apply<<<2048, 256, 0, stream>>>(out, stat, gamma, beta);
}

// Round 7
// 159.958 us; speedup vs baseline: 1.4490x; 1.4490x over previous
//
#include <hip/hip_runtime.h>
#include <cstdint>

#define NPTS   16384
#define BATCH  4
#define BNP    65536
#define CIN    64
#define KNB    16
#define COUT   128
#define BN_EPS 1e-5f

typedef __attribute__((ext_vector_type(8))) short     short8;
typedef __attribute__((ext_vector_type(4))) float     f32x4;
typedef __attribute__((ext_vector_type(2))) unsigned  u32x2;
typedef __attribute__((ext_vector_type(4))) int       i32x4;

__device__ __forceinline__ unsigned short f2bf(float f) {   // RNE
    unsigned u = __float_as_uint(f);
    u += 0x7FFFu + ((u >> 16) & 1u);
    return (unsigned short)(u >> 16);
}
__device__ __forceinline__ float bf2f(unsigned short h) {
    return __uint_as_float(((unsigned)h) << 16);
}

// ---- K0: feature [B][C][N] -> flat bf16 [B*N][64]; blk 1024: weight cvt ----
__global__ __launch_bounds__(256) void k_prep(const float* __restrict__ feat,
                                              unsigned short* __restrict__ fb,
                                              const float* __restrict__ Wm,
                                              const float* __restrict__ Wc,
                                              unsigned short* __restrict__ wmb,
                                              unsigned short* __restrict__ wcb)
{
    if (blockIdx.x == 1024) {           // aux block: bf16-ify weights
        #pragma unroll
        for (int i = threadIdx.x; i < CIN * CIN; i += 256)       wmb[i] = f2bf(Wm[i]);
        #pragma unroll
        for (int i = threadIdx.x; i < COUT * CIN; i += 256)      wcb[i] = f2bf(Wc[i]);
        return;
    }
    __shared__ float t[CIN][CIN + 1];
    int blk = blockIdx.x;
    int b   = blk >> 8;
    int n0  = (blk & 255) << 6;
    int sub = threadIdx.x >> 6, lane = threadIdx.x & 63;
    const float* fp = feat + (size_t)b * CIN * NPTS;
    #pragma unroll
    for (int r = 0; r < CIN; r += 4) {
        int c = r + sub;
        t[c][lane] = fp[(size_t)c * NPTS + n0 + lane];     // coalesced along n
    }
    __syncthreads();
    unsigned short* ob = fb + (size_t)(b * NPTS + n0) * CIN;
    #pragma unroll
    for (int r = 0; r < CIN; r += 4) {
        int x = r + sub;
        ob[(size_t)x * CIN + lane] = f2bf(t[lane][x]);     // row n0+x, ch=lane
    }
}

// ---------------- K1: gather+attention+linear -- R1 baseline, reg-ring gather ----------
// Clean A/B vs the proven 84us R1 kernel. Identical to R1 in: grid 512, 2 groups
// per wave, 8 waves/CU, direct per-wave stores, separate k_part, NO barriers or
// atomics in the loop or epilogue. ONLY change: gather is a 3-deep REGISTER ring
// (b1 frags: lane (ptc,qg) loads exactly its MFMA B-fragment bytes) plus a 3-deep
// sv ring for the P-inputs (R6's 1-deep sv reload = per-iter exposed latency;
// R5's global_load_lds = compiler vmcnt(0) drain per iter -- both regressed).
// rb refilled early (right after phase-1 consumes it), sv refilled after pack.
// acc2 stays MFMA-accumulated (AGPRs) -- pool-first = round-2/4 spill trap.
__global__ __launch_bounds__(256, 2) void k_main(
    const unsigned short* __restrict__ fb,   // [BNP][64] bf16
    const int* __restrict__ nidx,            // [BNP][16]
    const unsigned short* __restrict__ wmb,  // [64][64] bf16
    const unsigned short* __restrict__ wcb,  // [128][64] bf16
    float* __restrict__ out)                 // [4][128][16384], pre-BN
{
    __shared__ __align__(16) unsigned short plds[4][1152];   // 9.2 KB, wave-private

    const int tid  = threadIdx.x;
    const int wv   = tid >> 6;
    const int lane = tid & 63;
    const int ptc  = lane & 15;     // MFMA n / m index; gather row owner
    const int qg   = lane >> 4;     // quad group: owns ch qg*8..+7 (+32)
    const int p4   = ptc * 4;

    // ---- weight A-fragments in registers: A[m=lane&15][k=qg*8+j (+32*ks)] ----
    short8 wmF[4][2];
    #pragma unroll
    for (int mt = 0; mt < 4; ++mt)
        #pragma unroll
        for (int ks = 0; ks < 2; ++ks)
            wmF[mt][ks] = *(const short8*)&wmb[(size_t)(mt * 16 + ptc) * CIN + qg * 8 + ks * 32];
    short8 wcF[8][2];
    #pragma unroll
    for (int mt = 0; mt < 8; ++mt)
        #pragma unroll
        for (int ks = 0; ks < 2; ++ks)
            wcF[mt][ks] = *(const short8*)&wcb[(size_t)(mt * 16 + ptc) * CIN + qg * 8 + ks * 32];

    f32x4 acc2[8];
    #pragma unroll
    for (int i = 0; i < 8; ++i) acc2[i] = (f32x4){0.f, 0.f, 0.f, 0.f};

    for (int g = blockIdx.x * 4 + wv; g < BNP / KNB; g += 2048) {
        // group's 256 neighbor indices: lane holds idx flat [4*lane .. 4*lane+3];
        // idx[pt][j] lives in lane p4+(j>>2), elem j&3
        i32x4 iv = *(const i32x4*)(nidx + (size_t)g * 256 + lane * 4);

        // ---- register gather ring, depth 3 ----
        // lane (ptc,qg), row id=idx[ptc][k]:
        //   rb0 = ch qg*8..+7 (b1_0 frag), rb1 = ch 32+qg*8..+7 (b1_1 frag)
        //   svr[mt] = ch 16mt+4qg..+3 (P-inputs, matches MFMA C-layout rows)
        short8 rb0[3], rb1[3];
        u32x2  svr[3][4];
        #pragma unroll
        for (int kk = 0; kk < 3; ++kk) {
            int id = __shfl(iv[kk & 3], p4 + (kk >> 2));
            const unsigned short* gp = fb + (size_t)id * CIN;
            rb0[kk] = *(const short8*)(gp + qg * 8);
            rb1[kk] = *(const short8*)(gp + 32 + qg * 8);
            #pragma unroll
            for (int mt = 0; mt < 4; ++mt)
                svr[kk][mt] = *(const u32x2*)(gp + mt * 16 + qg * 4);
        }

        #pragma unroll
        for (int k = 0; k < KNB; ++k) {
            const int sl = k % 3;                          // static under full unroll

            // ---- phase 1: score^T[d, pt] = Wm x spir^T (B-frags from ring) ----
            short8 b1_0 = rb0[sl];
            short8 b1_1 = rb1[sl];
            f32x4 zero4 = (f32x4){0.f, 0.f, 0.f, 0.f};
            f32x4 a1[4];
            #pragma unroll
            for (int mt = 0; mt < 4; ++mt) {
                f32x4 t0 = __builtin_amdgcn_mfma_f32_16x16x32_bf16(wmF[mt][0], b1_0, zero4, 0, 0, 0);
                a1[mt]   = __builtin_amdgcn_mfma_f32_16x16x32_bf16(wmF[mt][1], b1_1, t0,    0, 0, 0);
            }

            // ---- early rb refill for k+3 (slot free once phase-1 issued) ----
            const unsigned short* gpn = fb;                // dummy init
            bool refill = (k + 3 < KNB);
            if (refill) {
                int id = __shfl(iv[(k + 3) & 3], p4 + ((k + 3) >> 2));
                gpn = fb + (size_t)id * CIN;
                rb0[sl] = *(const short8*)(gpn + qg * 8);
                rb1[sl] = *(const short8*)(gpn + 32 + qg * 8);
            }

            // ---- softmax over d: exp in place + xor16/xor32 ----
            float s = 0.f;
            #pragma unroll
            for (int mt = 0; mt < 4; ++mt)
                #pragma unroll
                for (int r = 0; r < 4; ++r) {
                    float x = __expf(a1[mt][r]);
                    a1[mt][r] = x;
                    s += x;
                }
            s += __shfl_xor(s, 16);
            s += __shfl_xor(s, 32);
            float inv = __builtin_amdgcn_rcpf(s);

            // ---- P = attn (.) spir -> plds (bf16, B-layout staging) ----
            unsigned short* pl = plds[wv];
            #pragma unroll
            for (int mt = 0; mt < 4; ++mt) {
                u32x2 sv = svr[sl][mt];                    // loaded 3 iters ago
                unsigned lo = sv[0], hi = sv[1];
                float p0 = bf2f((unsigned short)lo)         * (a1[mt][0] * inv);
                float p1 = bf2f((unsigned short)(lo >> 16)) * (a1[mt][1] * inv);
                float p2 = bf2f((unsigned short)hi)         * (a1[mt][2] * inv);
                float p3 = bf2f((unsigned short)(hi >> 16)) * (a1[mt][3] * inv);
                unsigned w0 = ((__float_as_uint(p0) + 0x8000u) >> 16) |
                              ((__float_as_uint(p1) + 0x8000u) & 0xFFFF0000u);
                unsigned w1 = ((__float_as_uint(p2) + 0x8000u) >> 16) |
                              ((__float_as_uint(p3) + 0x8000u) & 0xFFFF0000u);
                *(u32x2*)&pl[ptc * 72 + mt * 16 + qg * 4] = (u32x2){w0, w1};
            }

            // ---- late sv refill for k+3 (svr[sl] dead after pack) ----
            if (refill) {
                #pragma unroll
                for (int mt = 0; mt < 4; ++mt)
                    svr[sl][mt] = *(const u32x2*)(gpn + mt * 16 + qg * 4);
            }

            // ---- B2 frags: P[pt=lane&15][d=qg*8+j+32ks] ----
            short8 b2_0 = *(const short8*)&pl[ptc * 72 +      qg * 8];
            short8 b2_1 = *(const short8*)&pl[ptc * 72 + 32 + qg * 8];

            // ---- phase 2: acc2[o,pt] += Wc x P_k (fused pool+linear; AGPRs) ----
            #pragma unroll
            for (int mt = 0; mt < 8; ++mt) {
                acc2[mt] = __builtin_amdgcn_mfma_f32_16x16x32_bf16(wcF[mt][0], b2_0, acc2[mt], 0, 0, 0);
                acc2[mt] = __builtin_amdgcn_mfma_f32_16x16x32_bf16(wcF[mt][1], b2_1, acc2[mt], 0, 0, 0);
            }
        }

        // ---- epilogue: direct C-layout store (R1-proven), b_conv absorbed by BN ----
        int p0 = g * KNB;
        int b  = p0 >> 14;
        int nn = (p0 & (NPTS - 1)) + ptc;
        float* ob = out + (((size_t)b * COUT) << 14) + nn;
        #pragma unroll
        for (int mt = 0; mt < 8; ++mt)
            #pragma unroll
            for (int r = 0; r < 4; ++r) {
                ob[((size_t)(mt * 16 + qg * 4 + r)) << 14] = acc2[mt][r];
                acc2[mt][r] = 0.f;
            }
    }
}

// ---------------- K2: deterministic BN partials, one block per (o, b) ----------------
__global__ __launch_bounds__(256) void k_part(const float* __restrict__ out,
                                              float* __restrict__ part)
{
    int o = blockIdx.x >> 2, b = blockIdx.x & 3;
    const float4* p = (const float4*)(out + (((size_t)(b * COUT + o)) << 14));
    float s = 0.f, q = 0.f;
    for (int i = threadIdx.x; i < NPTS / 4; i += 256) {
        float4 v = p[i];
        s += (v.x + v.y) + (v.z + v.w);
        q += (v.x * v.x + v.y * v.y) + (v.z * v.z + v.w * v.w);
    }
    #pragma unroll
    for (int off = 32; off >= 1; off >>= 1) {
        s += __shfl_xor(s, off);
        q += __shfl_xor(q, off);
    }
    __shared__ float ls[4], lq[4];
    if ((threadIdx.x & 63) == 0) { ls[threadIdx.x >> 6] = s; lq[threadIdx.x >> 6] = q; }
    __syncthreads();
    if (threadIdx.x == 0) {
        part[blockIdx.x * 2]     = (ls[0] + ls[1]) + (ls[2] + ls[3]);
        part[blockIdx.x * 2 + 1] = (lq[0] + lq[1]) + (lq[2] + lq[3]);
    }
}

// ---------------- K3: finalize stats per block + apply BN in place ----------------
__global__ __launch_bounds__(256) void k_apply(float* __restrict__ out,
                                               const float* __restrict__ part,
                                               const float* __restrict__ gamma,
                                               const float* __restrict__ beta)
{
    __shared__ float sc[COUT], sh[COUT];
    int t = threadIdx.x;
    if (t < COUT) {
        float s = 0.f, q = 0.f;
        #pragma unroll
        for (int j = 0; j < 4; ++j) {
            s += part[(t * 4 + j) * 2];
            q += part[(t * 4 + j) * 2 + 1];
        }
        float mean = s * (1.0f / BNP);
        float var  = q * (1.0f / BNP) - mean * mean;
        float a = gamma[t] * rsqrtf(var + BN_EPS);
        sc[t] = a; sh[t] = beta[t] - mean * a;
    }
    __syncthreads();
    const int total4 = BATCH * COUT * NPTS / 4;
    for (long i = (long)blockIdx.x * 256 + t; i < total4; i += (long)gridDim.x * 256) {
        int ch = ((int)(i >> 12)) & 127;
        float4 v = ((float4*)out)[i];
        float a = sc[ch], b2 = sh[ch];
        v.x = fmaf(v.x, a, b2); v.y = fmaf(v.y, a, b2);
        v.z = fmaf(v.z, a, b2); v.w = fmaf(v.w, a, b2);
        ((float4*)out)[i] = v;
    }
}

extern "C" void kernel_launch(void* const* d_in, const int* in_sizes, int n_in,
                              void* d_out, int out_size, void* d_ws, size_t ws_size,
                              hipStream_t stream)
{
    const float* feat  = (const float*)d_in[0];
    const int*   nidx  = (const int*)  d_in[1];
    // d_in[2] = permatrix (unused); d_in[5] = b_conv (exactly absorbed by BN)
    const float* Wm    = (const float*)d_in[3];
    const float* Wc    = (const float*)d_in[4];
    const float* gamma = (const float*)d_in[6];
    const float* beta  = (const float*)d_in[7];
    float* out = (float*)d_out;

    char* ws = (char*)d_ws;
    unsigned short* fb   = (unsigned short*)ws;                       // 8.39 MB
    float*          part = (float*)(ws + (size_t)BNP * CIN * 2);      // 4 KB
    unsigned short* wmb  = (unsigned short*)(ws + (size_t)BNP * CIN * 2 + 4096);
    unsigned short* wcb  = wmb + CIN * CIN;                           // 8 KB + 16 KB

    k_prep <<<1025, 256, 0, stream>>>(feat, fb, Wm, Wc, wmb, wcb);
    k_main <<<512,  256, 0, stream>>>(fb, nidx, wmb, wcb, out);
    k_part <<<512,  256, 0, stream>>>(out, part);
    k_apply<<<2048, 256, 0, stream>>>(out, part, gamma, beta);
}